// Round 4
// baseline (212.777 us; speedup 1.0000x reference)
//
#include <hip/hip_runtime.h>
#include <cstdint>

typedef __bf16 bf16;
typedef __bf16 bf16x4 __attribute__((ext_vector_type(4)));
typedef __bf16 bf16x8 __attribute__((ext_vector_type(8)));
typedef float floatx4 __attribute__((ext_vector_type(4)));

#define MFMA32(a, b, c) __builtin_amdgcn_mfma_f32_16x16x32_bf16((a), (b), (c), 0, 0, 0)

__device__ inline bf16x8 cvt8(const float* p) {
    float4 u = *(const float4*)p;
    float4 v = *(const float4*)(p + 4);
    bf16x8 r;
    r[0] = (bf16)u.x; r[1] = (bf16)u.y; r[2] = (bf16)u.z; r[3] = (bf16)u.w;
    r[4] = (bf16)v.x; r[5] = (bf16)v.y; r[6] = (bf16)v.z; r[7] = (bf16)v.w;
    return r;
}

// ---------------------------------------------------------------------------
// Kernel 1: transpose + fp32->bf16 convert the four 512x512 weight matrices.
// ---------------------------------------------------------------------------
__global__ __launch_bounds__(256) void k_transpose(
    const float* __restrict__ w0, const float* __restrict__ w1,
    const float* __restrict__ w2, const float* __restrict__ w3,
    bf16* __restrict__ o0, bf16* __restrict__ o1,
    bf16* __restrict__ o2, bf16* __restrict__ o3)
{
    __shared__ float t[32][33];
    const float* in;
    bf16* out;
    switch (blockIdx.z) {
        case 0: in = w0; out = o0; break;
        case 1: in = w1; out = o1; break;
        case 2: in = w2; out = o2; break;
        default: in = w3; out = o3; break;
    }
    const int tx = threadIdx.x & 31;
    const int ty = threadIdx.x >> 5;
    const int r0 = blockIdx.y * 32;
    const int c0 = blockIdx.x * 32;
    #pragma unroll
    for (int i = 0; i < 32; i += 8)
        t[ty + i][tx] = in[(size_t)(r0 + ty + i) * 512 + c0 + tx];
    __syncthreads();
    #pragma unroll
    for (int i = 0; i < 32; i += 8)
        out[(size_t)(c0 + ty + i) * 512 + r0 + tx] = (bf16)t[tx][ty + i];
}

// ---------------------------------------------------------------------------
// Kernel 1b: X fp32 -> bf16 into d_out scratch (consumed by k_qkv).
// ---------------------------------------------------------------------------
__global__ __launch_bounds__(256) void k_cvtx(
    const float* __restrict__ X, bf16* __restrict__ Xb)
{
    const size_t idx = ((size_t)blockIdx.x * 256 + threadIdx.x) * 8;
    *(bf16x8*)(Xb + idx) = cvt8(X + idx);
}

// ---------------------------------------------------------------------------
// Kernel 2: QKV GEMM (128x128 tile, BK=32, double-buffered LDS) + per-wave
// LDS-transpose epilogue (coalesced 128B stores).
// ---------------------------------------------------------------------------
__global__ __launch_bounds__(256) void k_qkv(
    const bf16* __restrict__ Xb, const bf16* __restrict__ Wcat,
    const float* __restrict__ bq, const float* __restrict__ bk, const float* __restrict__ bv,
    bf16* __restrict__ Qs, bf16* __restrict__ Ks, bf16* __restrict__ Vt)
{
    __shared__ __align__(16) unsigned char smem[36864];   // 36 KB
    uint4* Al = (uint4*)smem;              // [2][512]
    uint4* Bl = (uint4*)(smem + 16384);    // [2][512]

    const int tid  = threadIdx.x;
    const int w    = tid >> 6;
    const int lane = tid & 63;
    const int col  = lane & 15;
    const int quad = lane >> 4;
    const int m0 = blockIdx.x * 128;
    const int n0 = blockIdx.y * 128;

    const bf16* gA0 = Xb   + (size_t)(m0 + (tid >> 2)) * 512 + (tid & 3) * 8;
    const bf16* gA1 = gA0 + 64 * 512;
    const bf16* gB0 = Wcat + (size_t)(n0 + (tid >> 2)) * 512 + (tid & 3) * 8;
    const bf16* gB1 = gB0 + 64 * 512;

    const floatx4 zf = {0.f, 0.f, 0.f, 0.f};
    floatx4 acc[4][4];
    #pragma unroll
    for (int a = 0; a < 4; ++a)
        #pragma unroll
        for (int b = 0; b < 4; ++b) acc[a][b] = zf;

    Al[tid]       = *(const uint4*)gA0;
    Al[tid + 256] = *(const uint4*)gA1;
    Bl[tid]       = *(const uint4*)gB0;
    Bl[tid + 256] = *(const uint4*)gB1;
    __syncthreads();

    const int mb = (w & 1) * 64;
    const int nb = (w >> 1) * 64;

    int buf = 0;
    for (int kk = 0; kk < 16; ++kk) {
        const int kn = ((kk + 1) & 15) * 32;
        const uint4 pa0 = *(const uint4*)(gA0 + kn);
        const uint4 pa1 = *(const uint4*)(gA1 + kn);
        const uint4 pb0 = *(const uint4*)(gB0 + kn);
        const uint4 pb1 = *(const uint4*)(gB1 + kn);

        const uint4* A4 = Al + buf * 512;
        const uint4* B4 = Bl + buf * 512;
        bf16x8 af[4], bfr[4];
        #pragma unroll
        for (int t = 0; t < 4; ++t) {
            union { uint4 u; bf16x8 v; } ca, cb;
            ca.u = A4[(mb + 16 * t + col) * 4 + quad];
            cb.u = B4[(nb + 16 * t + col) * 4 + quad];
            af[t] = ca.v;
            bfr[t] = cb.v;
        }
        #pragma unroll
        for (int tm = 0; tm < 4; ++tm)
            #pragma unroll
            for (int tn = 0; tn < 4; ++tn)
                acc[tm][tn] = MFMA32(af[tm], bfr[tn], acc[tm][tn]);

        const int nbuf = buf ^ 1;
        Al[nbuf * 512 + tid]       = pa0;
        Al[nbuf * 512 + tid + 256] = pa1;
        Bl[nbuf * 512 + tid]       = pb0;
        Bl[nbuf * 512 + tid + 256] = pb1;
        __syncthreads();
        buf = nbuf;
    }

    // ---- epilogue: wave-private LDS transpose, coalesced 128B stores ----
    bf16* ep = (bf16*)smem + (size_t)w * 64 * 72;   // 9216 B per wave

    const int which = blockIdx.y >> 2;              // 0=Q 1=K 2=V
    const int nbase = (blockIdx.y & 3) * 128 + nb;  // 64-aligned
    const int h  = nbase >> 6;
    const int mw = m0 + mb;
    const int b  = mw >> 12;
    const int s0 = mw & 4095;
    const float qsc = 0.125f * 1.44269504088896f;

    if (which == 2) {
        #pragma unroll
        for (int tn = 0; tn < 4; ++tn) {
            const int d = 16 * tn + col;
            const float bb = bv[nbase + d];
            #pragma unroll
            for (int tm = 0; tm < 4; ++tm) {
                union { bf16 e[4]; uint2 u; } pk;
                #pragma unroll
                for (int r = 0; r < 4; ++r) pk.e[r] = (bf16)(acc[tm][tn][r] + bb);
                *(uint2*)(ep + d * 72 + 16 * tm + 4 * quad) = pk.u;
            }
        }
    } else {
        const float* bias = (which == 0) ? bq : bk;
        const float sc = (which == 0) ? qsc : 1.0f;
        #pragma unroll
        for (int tn = 0; tn < 4; ++tn) {
            const int d = 16 * tn + col;
            const float bb = bias[nbase + d];
            #pragma unroll
            for (int tm = 0; tm < 4; ++tm)
                #pragma unroll
                for (int r = 0; r < 4; ++r)
                    ep[(16 * tm + 4 * quad + r) * 72 + d] = (bf16)((acc[tm][tn][r] + bb) * sc);
        }
    }

    asm volatile("" ::: "memory");

    const int rl = lane >> 3;
    const int ch = lane & 7;
    bf16* gbase;
    size_t rowstride;
    if (which == 2) {
        gbase = Vt + (((size_t)b * 8 + h) * 64) * 4096 + s0;
        rowstride = 4096;
    } else {
        bf16* P = (which == 0) ? Qs : Ks;
        gbase = P + (((size_t)b * 8 + h) * 4096 + s0) * 64;
        rowstride = 64;
    }
    #pragma unroll
    for (int it = 0; it < 8; ++it) {
        const int row = it * 8 + rl;
        const uint4 v = *(const uint4*)(ep + row * 72 + ch * 8);
        *(uint4*)(gbase + (size_t)row * rowstride + ch * 8) = v;
    }
}

// ---------------------------------------------------------------------------
// Kernel 3: attention. In-block split-K over keys (8 waves: 0-3 keys
// [0,2048), 4-7 keys [2048,4096)), transposed-score + in-lane P, PV via
// MFMA32 slot-bijection (R3).
// NEW (R4): K-step 64 — stage 64-key K/V tiles per half (64 KB LDS, still
// 2 blocks/CU). Halves the barrier count (64 -> 32) and widens the ILP
// window to 4 independent QK chains (t=0..3) x 2 q-sets feeding 2 PV
// groups, so the scheduler can overlap exp/pack of one tile with MFMA of
// another instead of convoying all 8 waves on the qk->exp->pv chain.
// Swizzles extend unchanged: row 32+r has the same &7 phase as row r.
// ---------------------------------------------------------------------------
__global__ __launch_bounds__(512, 4) void k_attn(
    const bf16* __restrict__ Qs, const bf16* __restrict__ Ks, const bf16* __restrict__ Vt,
    bf16* __restrict__ att)
{
    __shared__ __align__(16) unsigned char smem[65536];
    uint4* Klds = (uint4*)smem;                 // [half][2][512] uint4 = 32 KB
    uint4* Vlds = (uint4*)(smem + 32768);       // [half][2][512] uint4 = 32 KB
    float* Of   = (float*)smem;                 // combine alias: [4 wq][64 lane][8 frag][4]
    float* Ls   = (float*)(smem + 32768);       // combine alias: [4 wq][2 s][16 col]

    const int tid  = threadIdx.x;
    const int w    = tid >> 6;
    const int hf   = w >> 2;          // key-half: 0 = keys 0..2047, 1 = 2048..4095
    const int wq   = w & 3;           // q-subtile within block
    const int lane = tid & 63;
    const int col  = lane & 15;
    const int quad = lane >> 4;
    const int i    = blockIdx.x;
    const int bh   = ((i & 7) << 1) | ((i >> 3) & 1);   // 2 heads per XCD
    const int q0   = (i >> 4) * 128 + wq * 32;

    const bf16* Qb = Qs + (size_t)bh * 262144;
    const bf16* Kb = Ks + (size_t)bh * 262144 + (size_t)hf * 2048 * 64;
    const bf16* Vb = Vt + (size_t)bh * 262144 + (size_t)hf * 2048;

    // staging geometry: 256 threads per half stage a 64-key tile (2 rounds)
    const int t8  = tid & 255;
    const int rK  = t8 >> 3;
    const int lcK = (t8 & 7) ^ (rK & 7);
    const bf16* gK = Kb + (size_t)rK * 64 + lcK * 8;
    const int pV  = t8 >> 3;
    const int ccV = (t8 & 7) ^ (pV & 7);
    const int dV  = 2 * pV + (ccV >> 2);
    const int cV  = ccV & 3;
    const bf16* gV = Vb + (size_t)dV * 4096 + cV * 8;

    uint4* Kl2 = Klds + hf * 1024;   // this half's [2][512]
    uint4* Vl2 = Vlds + hf * 1024;

    // Q fragments (B-operand of S^T MFMA): 2 q-sets x 2 dim-halves
    bf16x8 aq[2][2];
    #pragma unroll
    for (int s = 0; s < 2; ++s)
        #pragma unroll
        for (int c = 0; c < 2; ++c)
            aq[s][c] = *(const bf16x8*)(Qb + (size_t)(q0 + 16 * s + col) * 64 + 32 * c + quad * 8);

    const floatx4 zf = {0.f, 0.f, 0.f, 0.f};
    floatx4 o[2][4];                 // O^T: [qset][d-tile]; lane d=4quad+r, q=col
    float lsum[2] = {0.f, 0.f};
    #pragma unroll
    for (int s = 0; s < 2; ++s)
        #pragma unroll
        for (int dt = 0; dt < 4; ++dt) o[s][dt] = zf;

    // V b64 read geometry (from the pair-swizzled uint4 tile)
    const int c1 = col & 1, ch2 = col >> 1, qh = quad >> 1, ql = quad & 1;

    Kl2[t8]       = *(const uint4*)gK;
    Kl2[t8 + 256] = *(const uint4*)(gK + 2048);   // rows 32..63 (+32*64 elems)
    Vl2[t8]       = *(const uint4*)gV;
    Vl2[t8 + 256] = *(const uint4*)(gV + 32);     // keys 32..63
    __syncthreads();

    int buf = 0;
    for (int kt = 0; kt < 2048; kt += 64) {
        const int kn = (kt + 64) & 2047;
        const uint4 kra = *(const uint4*)(gK + (size_t)kn * 64);
        const uint4 krb = *(const uint4*)(gK + (size_t)kn * 64 + 2048);
        const uint4 vra = *(const uint4*)(gV + kn);
        const uint4 vrb = *(const uint4*)(gV + kn + 32);

        const uint4* Kl = Kl2 + buf * 512;
        const uint2* Vl = (const uint2*)(Vl2 + buf * 512);

        // V^T A-fragments for both 32-key slices: vfrag8[g][dt] slot j holds
        // Vt[d=16dt+col][key = 32g + 16*(j>>2) + 4*quad + (j&3)]
        bf16x8 vfrag8[2][4];
        #pragma unroll
        for (int g = 0; g < 2; ++g) {
            const uint2* Vlg = Vl + g * 512;
            #pragma unroll
            for (int dt = 0; dt < 4; ++dt) {
                union { uint2 u[2]; bf16x8 v; } cv;
                #pragma unroll
                for (int th = 0; th < 2; ++th) {
                    const int slot = (dt * 8 + ch2) * 8 + ((c1 * 4 + 2 * th + qh) ^ ch2);
                    cv.u[th] = Vlg[slot * 2 + ql];
                }
                vfrag8[g][dt] = cv.v;
            }
        }

        // QK^T + exp for 4 tiles of 16 keys; pack P into per-slice bf16x8
        union PW { bf16 e[8]; bf16x8 v; };
        PW pws[2][2];     // [qset][kslice]
        #pragma unroll
        for (int t = 0; t < 4; ++t) {
            union { uint4 u; bf16x8 v; } k0, k1;
            k0.u = Kl[(16 * t + col) * 8 + (quad ^ (col & 7))];
            k1.u = Kl[(16 * t + col) * 8 + ((quad + 4) ^ (col & 7))];
            #pragma unroll
            for (int s = 0; s < 2; ++s) {
                floatx4 sc = MFMA32(k1.v, aq[s][1], MFMA32(k0.v, aq[s][0], zf));
                const float p0 = __builtin_amdgcn_exp2f(sc[0]);
                const float p1 = __builtin_amdgcn_exp2f(sc[1]);
                const float p2 = __builtin_amdgcn_exp2f(sc[2]);
                const float p3 = __builtin_amdgcn_exp2f(sc[3]);
                lsum[s] += (p0 + p1) + (p2 + p3);
                PW& pw = pws[s][t >> 1];
                const int e0 = 4 * (t & 1);
                pw.e[e0 + 0] = (bf16)p0; pw.e[e0 + 1] = (bf16)p1;
                pw.e[e0 + 2] = (bf16)p2; pw.e[e0 + 3] = (bf16)p3;
            }
        }

        #pragma unroll
        for (int s = 0; s < 2; ++s)
            #pragma unroll
            for (int dt = 0; dt < 4; ++dt) {
                o[s][dt] = MFMA32(vfrag8[0][dt], pws[s][0].v, o[s][dt]);
                o[s][dt] = MFMA32(vfrag8[1][dt], pws[s][1].v, o[s][dt]);
            }

        Kl2[(buf ^ 1) * 512 + t8]       = kra;
        Kl2[(buf ^ 1) * 512 + t8 + 256] = krb;
        Vl2[(buf ^ 1) * 512 + t8]       = vra;
        Vl2[(buf ^ 1) * 512 + t8 + 256] = vrb;
        __syncthreads();
        buf ^= 1;
    }

    // ---- partial l reduction (within this half's 2048 keys) ----
    float lv[2];
    #pragma unroll
    for (int s = 0; s < 2; ++s) {
        float v = lsum[s];
        v += __shfl_xor(v, 16, 64);
        v += __shfl_xor(v, 32, 64);
        lv[s] = v;
    }

    // ---- in-block split-K combine (LDS aliases staging bufs; all reads of
    // the staged tiles completed before the final in-loop barrier) ----
    float* op = Of + ((size_t)(wq * 64 + lane)) * 32;
    if (hf == 1) {
        #pragma unroll
        for (int s = 0; s < 2; ++s)
            #pragma unroll
            for (int dt = 0; dt < 4; ++dt) {
                const int f = s * 4 + dt;
                *(floatx4*)(op + ((f + lane) & 7) * 4) = o[s][dt];
            }
        if (quad == 0) {
            Ls[(wq * 2 + 0) * 16 + col] = lv[0];
            Ls[(wq * 2 + 1) * 16 + col] = lv[1];
        }
    }
    __syncthreads();
    if (hf == 0) {
        float inv[2];
        #pragma unroll
        for (int s = 0; s < 2; ++s)
            inv[s] = 1.0f / (lv[s] + Ls[(wq * 2 + s) * 16 + col]);
        const int b  = bh >> 3;
        const int hh = bh & 7;
        #pragma unroll
        for (int s = 0; s < 2; ++s)
            #pragma unroll
            for (int dt = 0; dt < 4; ++dt) {
                const int f = s * 4 + dt;
                const floatx4 po = *(const floatx4*)(op + ((f + lane) & 7) * 4);
                union { bf16 e[4]; uint2 u; } pk;
                #pragma unroll
                for (int r = 0; r < 4; ++r)
                    pk.e[r] = (bf16)((o[s][dt][r] + po[r]) * inv[s]);
                const size_t row = (size_t)b * 4096 + q0 + 16 * s + col;
                *(uint2*)(att + row * 512 + hh * 64 + 16 * dt + 4 * quad) = pk.u;
            }
    }
}

// ---------------------------------------------------------------------------
// Kernel 4: output projection GEMM. out[8192][512] fp32 = att @ Wto^T + bo.
// ---------------------------------------------------------------------------
__global__ __launch_bounds__(256) void k_oproj(
    const bf16* __restrict__ att, const bf16* __restrict__ Wto,
    const float* __restrict__ bo, float* __restrict__ out)
{
    __shared__ uint4 Al[2][512];
    __shared__ uint4 Bl[2][512];

    const int tid  = threadIdx.x;
    const int w    = tid >> 6;
    const int lane = tid & 63;
    const int col  = lane & 15;
    const int quad = lane >> 4;
    const int m0 = blockIdx.x * 128;
    const int n0 = blockIdx.y * 128;

    const bf16* gA0 = att + (size_t)(m0 + (tid >> 2)) * 512 + (tid & 3) * 8;
    const bf16* gA1 = gA0 + 64 * 512;
    const bf16* gB0 = Wto + (size_t)(n0 + (tid >> 2)) * 512 + (tid & 3) * 8;
    const bf16* gB1 = gB0 + 64 * 512;

    const floatx4 zf = {0.f, 0.f, 0.f, 0.f};
    floatx4 acc[4][4];
    #pragma unroll
    for (int a = 0; a < 4; ++a)
        #pragma unroll
        for (int b = 0; b < 4; ++b) acc[a][b] = zf;

    Al[0][tid]       = *(const uint4*)gA0;
    Al[0][tid + 256] = *(const uint4*)gA1;
    Bl[0][tid]       = *(const uint4*)gB0;
    Bl[0][tid + 256] = *(const uint4*)gB1;
    __syncthreads();

    const int mb = (w & 1) * 64;
    const int nb = (w >> 1) * 64;

    int buf = 0;
    for (int kk = 0; kk < 16; ++kk) {
        const int kn = ((kk + 1) & 15) * 32;
        const uint4 pa0 = *(const uint4*)(gA0 + kn);
        const uint4 pa1 = *(const uint4*)(gA1 + kn);
        const uint4 pb0 = *(const uint4*)(gB0 + kn);
        const uint4 pb1 = *(const uint4*)(gB1 + kn);

        const uint4* A4 = Al[buf];
        const uint4* B4 = Bl[buf];
        bf16x8 af[4], bfr[4];
        #pragma unroll
        for (int t = 0; t < 4; ++t) {
            union { uint4 u; bf16x8 v; } ca, cb;
            ca.u = A4[(mb + 16 * t + col) * 4 + quad];
            cb.u = B4[(nb + 16 * t + col) * 4 + quad];
            af[t] = ca.v;
            bfr[t] = cb.v;
        }
        #pragma unroll
        for (int tm = 0; tm < 4; ++tm)
            #pragma unroll
            for (int tn = 0; tn < 4; ++tn)
                acc[tm][tn] = MFMA32(af[tm], bfr[tn], acc[tm][tn]);

        Al[buf ^ 1][tid]       = pa0;
        Al[buf ^ 1][tid + 256] = pa1;
        Bl[buf ^ 1][tid]       = pb0;
        Bl[buf ^ 1][tid + 256] = pb1;
        __syncthreads();
        buf ^= 1;
    }

    #pragma unroll
    for (int tn = 0; tn < 4; ++tn) {
        const int n = n0 + nb + 16 * tn + col;
        const float bb = bo[n];
        #pragma unroll
        for (int tm = 0; tm < 4; ++tm)
            #pragma unroll
            for (int r = 0; r < 4; ++r) {
                const int m = m0 + mb + 16 * tm + quad * 4 + r;
                out[(size_t)m * 512 + n] = acc[tm][tn][r] + bb;
            }
    }
}

// ---------------------------------------------------------------------------
extern "C" void kernel_launch(void* const* d_in, const int* in_sizes, int n_in,
                              void* d_out, int out_size, void* d_ws, size_t ws_size,
                              hipStream_t stream)
{
    const float* X  = (const float*)d_in[0];
    const float* Wq = (const float*)d_in[1];
    const float* bq = (const float*)d_in[2];
    const float* Wk = (const float*)d_in[3];
    const float* bk = (const float*)d_in[4];
    const float* Wv = (const float*)d_in[5];
    const float* bv = (const float*)d_in[6];
    const float* Wo = (const float*)d_in[7];
    const float* bo = (const float*)d_in[8];

    // workspace (bf16 elements): Wcat(3) + Wto + Q + K + Vt + att = 34.1 MB
    bf16* Wtq = (bf16*)d_ws;                   // rows 0..511 of Wcat
    bf16* Wtk = Wtq + 512 * 512;               // rows 512..1023
    bf16* Wtv = Wtk + 512 * 512;               // rows 1024..1535
    bf16* Wto = Wtv + 512 * 512;
    bf16* Qs  = Wto + 512 * 512;               // [16][4096][64]
    bf16* Ks  = Qs + (size_t)16 * 4096 * 64;   // [16][4096][64]
    bf16* Vt  = Ks + (size_t)16 * 4096 * 64;   // [16][64][4096]
    bf16* att = Vt + (size_t)16 * 4096 * 64;   // [8192][512]

    bf16* Xb  = (bf16*)d_out;                  // scratch; consumed by k_qkv,
                                               // d_out rewritten only by k_oproj

    k_transpose<<<dim3(16, 16, 4), 256, 0, stream>>>(Wq, Wk, Wv, Wo, Wtq, Wtk, Wtv, Wto);
    k_cvtx<<<2048, 256, 0, stream>>>(X, Xb);
    k_qkv<<<dim3(64, 12), 256, 0, stream>>>(Xb, Wtq, bq, bk, bv, Qs, Ks, Vt);
    k_attn<<<512, 512, 0, stream>>>(Qs, Ks, Vt, att);
    k_oproj<<<dim3(64, 4), 256, 0, stream>>>(att, Wto, bo, (float*)d_out);
}

// Round 5
// 194.598 us; speedup vs baseline: 1.0934x; 1.0934x over previous
//
#include <hip/hip_runtime.h>
#include <cstdint>

typedef __bf16 bf16;
typedef __bf16 bf16x4 __attribute__((ext_vector_type(4)));
typedef __bf16 bf16x8 __attribute__((ext_vector_type(8)));
typedef float floatx4 __attribute__((ext_vector_type(4)));

#define MFMA32(a, b, c) __builtin_amdgcn_mfma_f32_16x16x32_bf16((a), (b), (c), 0, 0, 0)

__device__ inline bf16x8 cvt8(const float* p) {
    float4 u = *(const float4*)p;
    float4 v = *(const float4*)(p + 4);
    bf16x8 r;
    r[0] = (bf16)u.x; r[1] = (bf16)u.y; r[2] = (bf16)u.z; r[3] = (bf16)u.w;
    r[4] = (bf16)v.x; r[5] = (bf16)v.y; r[6] = (bf16)v.z; r[7] = (bf16)v.w;
    return r;
}

// ---------------------------------------------------------------------------
// Kernel 1: transpose + fp32->bf16 convert the four 512x512 weight matrices.
// ---------------------------------------------------------------------------
__global__ __launch_bounds__(256) void k_transpose(
    const float* __restrict__ w0, const float* __restrict__ w1,
    const float* __restrict__ w2, const float* __restrict__ w3,
    bf16* __restrict__ o0, bf16* __restrict__ o1,
    bf16* __restrict__ o2, bf16* __restrict__ o3)
{
    __shared__ float t[32][33];
    const float* in;
    bf16* out;
    switch (blockIdx.z) {
        case 0: in = w0; out = o0; break;
        case 1: in = w1; out = o1; break;
        case 2: in = w2; out = o2; break;
        default: in = w3; out = o3; break;
    }
    const int tx = threadIdx.x & 31;
    const int ty = threadIdx.x >> 5;
    const int r0 = blockIdx.y * 32;
    const int c0 = blockIdx.x * 32;
    #pragma unroll
    for (int i = 0; i < 32; i += 8)
        t[ty + i][tx] = in[(size_t)(r0 + ty + i) * 512 + c0 + tx];
    __syncthreads();
    #pragma unroll
    for (int i = 0; i < 32; i += 8)
        out[(size_t)(c0 + ty + i) * 512 + r0 + tx] = (bf16)t[tx][ty + i];
}

// ---------------------------------------------------------------------------
// Kernel 1b: X fp32 -> bf16 into d_out scratch (consumed by k_qkv).
// ---------------------------------------------------------------------------
__global__ __launch_bounds__(256) void k_cvtx(
    const float* __restrict__ X, bf16* __restrict__ Xb)
{
    const size_t idx = ((size_t)blockIdx.x * 256 + threadIdx.x) * 8;
    *(bf16x8*)(Xb + idx) = cvt8(X + idx);
}

// ---------------------------------------------------------------------------
// Kernel 2: QKV GEMM (128x128 tile, BK=32, double-buffered LDS) + per-wave
// LDS-transpose epilogue (coalesced 128B stores).
// ---------------------------------------------------------------------------
__global__ __launch_bounds__(256) void k_qkv(
    const bf16* __restrict__ Xb, const bf16* __restrict__ Wcat,
    const float* __restrict__ bq, const float* __restrict__ bk, const float* __restrict__ bv,
    bf16* __restrict__ Qs, bf16* __restrict__ Ks, bf16* __restrict__ Vt)
{
    __shared__ __align__(16) unsigned char smem[36864];   // 36 KB
    uint4* Al = (uint4*)smem;              // [2][512]
    uint4* Bl = (uint4*)(smem + 16384);    // [2][512]

    const int tid  = threadIdx.x;
    const int w    = tid >> 6;
    const int lane = tid & 63;
    const int col  = lane & 15;
    const int quad = lane >> 4;
    const int m0 = blockIdx.x * 128;
    const int n0 = blockIdx.y * 128;

    const bf16* gA0 = Xb   + (size_t)(m0 + (tid >> 2)) * 512 + (tid & 3) * 8;
    const bf16* gA1 = gA0 + 64 * 512;
    const bf16* gB0 = Wcat + (size_t)(n0 + (tid >> 2)) * 512 + (tid & 3) * 8;
    const bf16* gB1 = gB0 + 64 * 512;

    const floatx4 zf = {0.f, 0.f, 0.f, 0.f};
    floatx4 acc[4][4];
    #pragma unroll
    for (int a = 0; a < 4; ++a)
        #pragma unroll
        for (int b = 0; b < 4; ++b) acc[a][b] = zf;

    Al[tid]       = *(const uint4*)gA0;
    Al[tid + 256] = *(const uint4*)gA1;
    Bl[tid]       = *(const uint4*)gB0;
    Bl[tid + 256] = *(const uint4*)gB1;
    __syncthreads();

    const int mb = (w & 1) * 64;
    const int nb = (w >> 1) * 64;

    int buf = 0;
    for (int kk = 0; kk < 16; ++kk) {
        const int kn = ((kk + 1) & 15) * 32;
        const uint4 pa0 = *(const uint4*)(gA0 + kn);
        const uint4 pa1 = *(const uint4*)(gA1 + kn);
        const uint4 pb0 = *(const uint4*)(gB0 + kn);
        const uint4 pb1 = *(const uint4*)(gB1 + kn);

        const uint4* A4 = Al + buf * 512;
        const uint4* B4 = Bl + buf * 512;
        bf16x8 af[4], bfr[4];
        #pragma unroll
        for (int t = 0; t < 4; ++t) {
            union { uint4 u; bf16x8 v; } ca, cb;
            ca.u = A4[(mb + 16 * t + col) * 4 + quad];
            cb.u = B4[(nb + 16 * t + col) * 4 + quad];
            af[t] = ca.v;
            bfr[t] = cb.v;
        }
        #pragma unroll
        for (int tm = 0; tm < 4; ++tm)
            #pragma unroll
            for (int tn = 0; tn < 4; ++tn)
                acc[tm][tn] = MFMA32(af[tm], bfr[tn], acc[tm][tn]);

        const int nbuf = buf ^ 1;
        Al[nbuf * 512 + tid]       = pa0;
        Al[nbuf * 512 + tid + 256] = pa1;
        Bl[nbuf * 512 + tid]       = pb0;
        Bl[nbuf * 512 + tid + 256] = pb1;
        __syncthreads();
        buf = nbuf;
    }

    // ---- epilogue: wave-private LDS transpose, coalesced 128B stores ----
    bf16* ep = (bf16*)smem + (size_t)w * 64 * 72;   // 9216 B per wave

    const int which = blockIdx.y >> 2;              // 0=Q 1=K 2=V
    const int nbase = (blockIdx.y & 3) * 128 + nb;  // 64-aligned
    const int h  = nbase >> 6;
    const int mw = m0 + mb;
    const int b  = mw >> 12;
    const int s0 = mw & 4095;
    const float qsc = 0.125f * 1.44269504088896f;

    if (which == 2) {
        #pragma unroll
        for (int tn = 0; tn < 4; ++tn) {
            const int d = 16 * tn + col;
            const float bb = bv[nbase + d];
            #pragma unroll
            for (int tm = 0; tm < 4; ++tm) {
                union { bf16 e[4]; uint2 u; } pk;
                #pragma unroll
                for (int r = 0; r < 4; ++r) pk.e[r] = (bf16)(acc[tm][tn][r] + bb);
                *(uint2*)(ep + d * 72 + 16 * tm + 4 * quad) = pk.u;
            }
        }
    } else {
        const float* bias = (which == 0) ? bq : bk;
        const float sc = (which == 0) ? qsc : 1.0f;
        #pragma unroll
        for (int tn = 0; tn < 4; ++tn) {
            const int d = 16 * tn + col;
            const float bb = bias[nbase + d];
            #pragma unroll
            for (int tm = 0; tm < 4; ++tm)
                #pragma unroll
                for (int r = 0; r < 4; ++r)
                    ep[(16 * tm + 4 * quad + r) * 72 + d] = (bf16)((acc[tm][tn][r] + bb) * sc);
        }
    }

    asm volatile("" ::: "memory");

    const int rl = lane >> 3;
    const int ch = lane & 7;
    bf16* gbase;
    size_t rowstride;
    if (which == 2) {
        gbase = Vt + (((size_t)b * 8 + h) * 64) * 4096 + s0;
        rowstride = 4096;
    } else {
        bf16* P = (which == 0) ? Qs : Ks;
        gbase = P + (((size_t)b * 8 + h) * 4096 + s0) * 64;
        rowstride = 64;
    }
    #pragma unroll
    for (int it = 0; it < 8; ++it) {
        const int row = it * 8 + rl;
        const uint4 v = *(const uint4*)(ep + row * 72 + ch * 8);
        *(uint4*)(gbase + (size_t)row * rowstride + ch * 8) = v;
    }
}

// ---------------------------------------------------------------------------
// Kernel 3: attention. In-block split-K over keys (8 waves: 0-3 keys
// [0,2048), 4-7 keys [2048,4096)), transposed-score + in-lane P, PV via
// MFMA32 slot-bijection. K-step 32 (R3 structure — K-step 64 spilled).
// NEW (R5): amdgpu_waves_per_eu(4,4). Under (512,4) the compiler clamped to
// the 8-waves/EU tier (VGPR_Count=64) even though the grid only ever gives
// 4 waves/EU (512 blocks = 2 blocks/CU) — the live set (~78 data regs +
// addresses) doesn't fit in 64, so every iteration rematerializes LDS
// addresses and shuffles data: measured ~200 VALU instrs/wave-iter vs ~80
// needed (VALUBusy 52.7%, the true bottleneck). Pinning waves/EU to 4
// gives the allocator the full 128-VGPR budget at ZERO occupancy cost.
// ---------------------------------------------------------------------------
__global__ __launch_bounds__(512) __attribute__((amdgpu_waves_per_eu(4, 4))) void k_attn(
    const bf16* __restrict__ Qs, const bf16* __restrict__ Ks, const bf16* __restrict__ Vt,
    bf16* __restrict__ att)
{
    __shared__ __align__(16) unsigned char smem[33280];
    uint4* Klds = (uint4*)smem;                 // [half][2][256]
    uint4* Vlds = (uint4*)(smem + 16384);       // [half][2][256]
    float* Of   = (float*)smem;                 // combine: [4 wq][64 lane][8 frag][4]
    float* Ls   = (float*)(smem + 32768);       // [4 wq][2 s][16 col]

    const int tid  = threadIdx.x;
    const int w    = tid >> 6;
    const int hf   = w >> 2;          // key-half: 0 = keys 0..2047, 1 = 2048..4095
    const int wq   = w & 3;           // q-subtile within block
    const int lane = tid & 63;
    const int col  = lane & 15;
    const int quad = lane >> 4;
    const int i    = blockIdx.x;
    const int bh   = ((i & 7) << 1) | ((i >> 3) & 1);   // 2 heads per XCD
    const int q0   = (i >> 4) * 128 + wq * 32;

    const bf16* Qb = Qs + (size_t)bh * 262144;
    const bf16* Kb = Ks + (size_t)bh * 262144 + (size_t)hf * 2048 * 64;
    const bf16* Vb = Vt + (size_t)bh * 262144 + (size_t)hf * 2048;

    // staging geometry: threads tid&255 within each half (staging group ==
    // compute group: tid<256 <=> hf==0)
    const int t8  = tid & 255;
    const int rK  = t8 >> 3;
    const int lcK = (t8 & 7) ^ (rK & 7);
    const bf16* gK = Kb + (size_t)rK * 64 + lcK * 8;
    const int pV  = t8 >> 3;
    const int ccV = (t8 & 7) ^ (pV & 7);
    const int dV  = 2 * pV + (ccV >> 2);
    const int cV  = ccV & 3;
    const bf16* gV = Vb + (size_t)dV * 4096 + cV * 8;

    uint4* Kl2 = Klds + hf * 512;   // this half's [2][256]
    uint4* Vl2 = Vlds + hf * 512;

    // Q fragments (B-operand of S^T MFMA): 2 q-sets x 2 dim-halves
    bf16x8 aq[2][2];
    #pragma unroll
    for (int s = 0; s < 2; ++s)
        #pragma unroll
        for (int c = 0; c < 2; ++c)
            aq[s][c] = *(const bf16x8*)(Qb + (size_t)(q0 + 16 * s + col) * 64 + 32 * c + quad * 8);

    const floatx4 zf = {0.f, 0.f, 0.f, 0.f};
    floatx4 o[2][4];                 // O^T: [qset][d-tile]; lane d=4quad+r, q=col
    float lsum[2] = {0.f, 0.f};
    #pragma unroll
    for (int s = 0; s < 2; ++s)
        #pragma unroll
        for (int dt = 0; dt < 4; ++dt) o[s][dt] = zf;

    // V b64 read geometry (from the pair-swizzled uint4 tile)
    const int c1 = col & 1, ch2 = col >> 1, qh = quad >> 1, ql = quad & 1;

    Kl2[t8] = *(const uint4*)gK;
    Vl2[t8] = *(const uint4*)gV;
    __syncthreads();

    int buf = 0;
    for (int kt = 0; kt < 2048; kt += 32) {
        const int kn = (kt + 32) & 2047;
        const uint4 kreg = *(const uint4*)(gK + (size_t)kn * 64);
        const uint4 vreg = *(const uint4*)(gV + kn);

        const uint4* Kl = Kl2 + buf * 256;
        const uint2* Vl = (const uint2*)(Vl2 + buf * 256);

        bf16x8 kf[2][2];
        #pragma unroll
        for (int t = 0; t < 2; ++t)
            #pragma unroll
            for (int c = 0; c < 2; ++c) {
                union { uint4 u; bf16x8 v; } cv;
                cv.u = Kl[(16 * t + col) * 8 + ((quad + 4 * c) ^ (col & 7))];
                kf[t][c] = cv.v;
            }
        // V^T A-fragments, both key-halves packed: vfrag8[dt] slot j holds
        // Vt[d=16dt+col][key = 16*(j>>2) + 4*quad + (j&3)]
        bf16x8 vfrag8[4];
        #pragma unroll
        for (int dt = 0; dt < 4; ++dt) {
            union { uint2 u[2]; bf16x8 v; } cv;
            #pragma unroll
            for (int t = 0; t < 2; ++t) {
                const int slot = (dt * 8 + ch2) * 8 + ((c1 * 4 + 2 * t + qh) ^ ch2);
                cv.u[t] = Vl[slot * 2 + ql];
            }
            vfrag8[dt] = cv.v;
        }

        #pragma unroll
        for (int s = 0; s < 2; ++s) {
            // P^T B-fragment: slot j = exp(score of key 16*(j>>2)+4*quad+(j&3))
            union { bf16 e[8]; bf16x8 v; } pw;
            #pragma unroll
            for (int t = 0; t < 2; ++t) {
                floatx4 sc = MFMA32(kf[t][1], aq[s][1], MFMA32(kf[t][0], aq[s][0], zf));
                const float p0 = __builtin_amdgcn_exp2f(sc[0]);
                const float p1 = __builtin_amdgcn_exp2f(sc[1]);
                const float p2 = __builtin_amdgcn_exp2f(sc[2]);
                const float p3 = __builtin_amdgcn_exp2f(sc[3]);
                lsum[s] += (p0 + p1) + (p2 + p3);
                pw.e[4 * t + 0] = (bf16)p0; pw.e[4 * t + 1] = (bf16)p1;
                pw.e[4 * t + 2] = (bf16)p2; pw.e[4 * t + 3] = (bf16)p3;
            }
            #pragma unroll
            for (int dt = 0; dt < 4; ++dt)
                o[s][dt] = MFMA32(vfrag8[dt], pw.v, o[s][dt]);
        }

        Kl2[(buf ^ 1) * 256 + t8] = kreg;
        Vl2[(buf ^ 1) * 256 + t8] = vreg;
        __syncthreads();
        buf ^= 1;
    }

    // ---- partial l reduction (within this half's 2048 keys) ----
    float lv[2];
    #pragma unroll
    for (int s = 0; s < 2; ++s) {
        float v = lsum[s];
        v += __shfl_xor(v, 16, 64);
        v += __shfl_xor(v, 32, 64);
        lv[s] = v;
    }

    // ---- in-block split-K combine (LDS aliases staging bufs; all reads of
    // the staged tiles completed before the final in-loop barrier) ----
    float* op = Of + ((size_t)(wq * 64 + lane)) * 32;
    if (hf == 1) {
        #pragma unroll
        for (int s = 0; s < 2; ++s)
            #pragma unroll
            for (int dt = 0; dt < 4; ++dt) {
                const int f = s * 4 + dt;
                *(floatx4*)(op + ((f + lane) & 7) * 4) = o[s][dt];
            }
        if (quad == 0) {
            Ls[(wq * 2 + 0) * 16 + col] = lv[0];
            Ls[(wq * 2 + 1) * 16 + col] = lv[1];
        }
    }
    __syncthreads();
    if (hf == 0) {
        float inv[2];
        #pragma unroll
        for (int s = 0; s < 2; ++s)
            inv[s] = 1.0f / (lv[s] + Ls[(wq * 2 + s) * 16 + col]);
        const int b  = bh >> 3;
        const int hh = bh & 7;
        #pragma unroll
        for (int s = 0; s < 2; ++s)
            #pragma unroll
            for (int dt = 0; dt < 4; ++dt) {
                const int f = s * 4 + dt;
                const floatx4 po = *(const floatx4*)(op + ((f + lane) & 7) * 4);
                union { bf16 e[4]; uint2 u; } pk;
                #pragma unroll
                for (int r = 0; r < 4; ++r)
                    pk.e[r] = (bf16)((o[s][dt][r] + po[r]) * inv[s]);
                const size_t row = (size_t)b * 4096 + q0 + 16 * s + col;
                *(uint2*)(att + row * 512 + hh * 64 + 16 * dt + 4 * quad) = pk.u;
            }
    }
}

// ---------------------------------------------------------------------------
// Kernel 4: output projection GEMM. out[8192][512] fp32 = att @ Wto^T + bo.
// ---------------------------------------------------------------------------
__global__ __launch_bounds__(256) void k_oproj(
    const bf16* __restrict__ att, const bf16* __restrict__ Wto,
    const float* __restrict__ bo, float* __restrict__ out)
{
    __shared__ uint4 Al[2][512];
    __shared__ uint4 Bl[2][512];

    const int tid  = threadIdx.x;
    const int w    = tid >> 6;
    const int lane = tid & 63;
    const int col  = lane & 15;
    const int quad = lane >> 4;
    const int m0 = blockIdx.x * 128;
    const int n0 = blockIdx.y * 128;

    const bf16* gA0 = att + (size_t)(m0 + (tid >> 2)) * 512 + (tid & 3) * 8;
    const bf16* gA1 = gA0 + 64 * 512;
    const bf16* gB0 = Wto + (size_t)(n0 + (tid >> 2)) * 512 + (tid & 3) * 8;
    const bf16* gB1 = gB0 + 64 * 512;

    const floatx4 zf = {0.f, 0.f, 0.f, 0.f};
    floatx4 acc[4][4];
    #pragma unroll
    for (int a = 0; a < 4; ++a)
        #pragma unroll
        for (int b = 0; b < 4; ++b) acc[a][b] = zf;

    Al[0][tid]       = *(const uint4*)gA0;
    Al[0][tid + 256] = *(const uint4*)gA1;
    Bl[0][tid]       = *(const uint4*)gB0;
    Bl[0][tid + 256] = *(const uint4*)gB1;
    __syncthreads();

    const int mb = (w & 1) * 64;
    const int nb = (w >> 1) * 64;

    int buf = 0;
    for (int kk = 0; kk < 16; ++kk) {
        const int kn = ((kk + 1) & 15) * 32;
        const uint4 pa0 = *(const uint4*)(gA0 + kn);
        const uint4 pa1 = *(const uint4*)(gA1 + kn);
        const uint4 pb0 = *(const uint4*)(gB0 + kn);
        const uint4 pb1 = *(const uint4*)(gB1 + kn);

        const uint4* A4 = Al[buf];
        const uint4* B4 = Bl[buf];
        bf16x8 af[4], bfr[4];
        #pragma unroll
        for (int t = 0; t < 4; ++t) {
            union { uint4 u; bf16x8 v; } ca, cb;
            ca.u = A4[(mb + 16 * t + col) * 4 + quad];
            cb.u = B4[(nb + 16 * t + col) * 4 + quad];
            af[t] = ca.v;
            bfr[t] = cb.v;
        }
        #pragma unroll
        for (int tm = 0; tm < 4; ++tm)
            #pragma unroll
            for (int tn = 0; tn < 4; ++tn)
                acc[tm][tn] = MFMA32(af[tm], bfr[tn], acc[tm][tn]);

        Al[buf ^ 1][tid]       = pa0;
        Al[buf ^ 1][tid + 256] = pa1;
        Bl[buf ^ 1][tid]       = pb0;
        Bl[buf ^ 1][tid + 256] = pb1;
        __syncthreads();
        buf ^= 1;
    }

    #pragma unroll
    for (int tn = 0; tn < 4; ++tn) {
        const int n = n0 + nb + 16 * tn + col;
        const float bb = bo[n];
        #pragma unroll
        for (int tm = 0; tm < 4; ++tm)
            #pragma unroll
            for (int r = 0; r < 4; ++r) {
                const int m = m0 + mb + 16 * tm + quad * 4 + r;
                out[(size_t)m * 512 + n] = acc[tm][tn][r] + bb;
            }
    }
}

// ---------------------------------------------------------------------------
extern "C" void kernel_launch(void* const* d_in, const int* in_sizes, int n_in,
                              void* d_out, int out_size, void* d_ws, size_t ws_size,
                              hipStream_t stream)
{
    const float* X  = (const float*)d_in[0];
    const float* Wq = (const float*)d_in[1];
    const float* bq = (const float*)d_in[2];
    const float* Wk = (const float*)d_in[3];
    const float* bk = (const float*)d_in[4];
    const float* Wv = (const float*)d_in[5];
    const float* bv = (const float*)d_in[6];
    const float* Wo = (const float*)d_in[7];
    const float* bo = (const float*)d_in[8];

    // workspace (bf16 elements): Wcat(3) + Wto + Q + K + Vt + att = 34.1 MB
    bf16* Wtq = (bf16*)d_ws;                   // rows 0..511 of Wcat
    bf16* Wtk = Wtq + 512 * 512;               // rows 512..1023
    bf16* Wtv = Wtk + 512 * 512;               // rows 1024..1535
    bf16* Wto = Wtv + 512 * 512;
    bf16* Qs  = Wto + 512 * 512;               // [16][4096][64]
    bf16* Ks  = Qs + (size_t)16 * 4096 * 64;   // [16][4096][64]
    bf16* Vt  = Ks + (size_t)16 * 4096 * 64;   // [16][64][4096]
    bf16* att = Vt + (size_t)16 * 4096 * 64;   // [8192][512]

    bf16* Xb  = (bf16*)d_out;                  // scratch; consumed by k_qkv,
                                               // d_out rewritten only by k_oproj

    k_transpose<<<dim3(16, 16, 4), 256, 0, stream>>>(Wq, Wk, Wv, Wo, Wtq, Wtk, Wtv, Wto);
    k_cvtx<<<2048, 256, 0, stream>>>(X, Xb);
    k_qkv<<<dim3(64, 12), 256, 0, stream>>>(Xb, Wtq, bq, bk, bv, Qs, Ks, Vt);
    k_attn<<<512, 512, 0, stream>>>(Qs, Ks, Vt, att);
    k_oproj<<<dim3(64, 4), 256, 0, stream>>>(att, Wto, bo, (float*)d_out);
}

// Round 6
// 190.973 us; speedup vs baseline: 1.1142x; 1.0190x over previous
//
#include <hip/hip_runtime.h>
#include <cstdint>

typedef __bf16 bf16;
typedef __bf16 bf16x4 __attribute__((ext_vector_type(4)));
typedef __bf16 bf16x8 __attribute__((ext_vector_type(8)));
typedef float floatx4 __attribute__((ext_vector_type(4)));

#define MFMA32(a, b, c) __builtin_amdgcn_mfma_f32_16x16x32_bf16((a), (b), (c), 0, 0, 0)

__device__ inline bf16x8 cvt8(const float* p) {
    float4 u = *(const float4*)p;
    float4 v = *(const float4*)(p + 4);
    bf16x8 r;
    r[0] = (bf16)u.x; r[1] = (bf16)u.y; r[2] = (bf16)u.z; r[3] = (bf16)u.w;
    r[4] = (bf16)v.x; r[5] = (bf16)v.y; r[6] = (bf16)v.z; r[7] = (bf16)v.w;
    return r;
}

// ---------------------------------------------------------------------------
// Kernel 1: transpose + fp32->bf16 convert the four 512x512 weight matrices.
// ---------------------------------------------------------------------------
__global__ __launch_bounds__(256) void k_transpose(
    const float* __restrict__ w0, const float* __restrict__ w1,
    const float* __restrict__ w2, const float* __restrict__ w3,
    bf16* __restrict__ o0, bf16* __restrict__ o1,
    bf16* __restrict__ o2, bf16* __restrict__ o3)
{
    __shared__ float t[32][33];
    const float* in;
    bf16* out;
    switch (blockIdx.z) {
        case 0: in = w0; out = o0; break;
        case 1: in = w1; out = o1; break;
        case 2: in = w2; out = o2; break;
        default: in = w3; out = o3; break;
    }
    const int tx = threadIdx.x & 31;
    const int ty = threadIdx.x >> 5;
    const int r0 = blockIdx.y * 32;
    const int c0 = blockIdx.x * 32;
    #pragma unroll
    for (int i = 0; i < 32; i += 8)
        t[ty + i][tx] = in[(size_t)(r0 + ty + i) * 512 + c0 + tx];
    __syncthreads();
    #pragma unroll
    for (int i = 0; i < 32; i += 8)
        out[(size_t)(c0 + ty + i) * 512 + r0 + tx] = (bf16)t[tx][ty + i];
}

// ---------------------------------------------------------------------------
// Kernel 1b: X fp32 -> bf16 into d_out scratch (consumed by k_qkv).
// ---------------------------------------------------------------------------
__global__ __launch_bounds__(256) void k_cvtx(
    const float* __restrict__ X, bf16* __restrict__ Xb)
{
    const size_t idx = ((size_t)blockIdx.x * 256 + threadIdx.x) * 8;
    *(bf16x8*)(Xb + idx) = cvt8(X + idx);
}

// ---------------------------------------------------------------------------
// Kernel 2: QKV GEMM (128x128 tile, BK=32, double-buffered LDS) + per-wave
// LDS-transpose epilogue (coalesced 128B stores).
// ---------------------------------------------------------------------------
__global__ __launch_bounds__(256) void k_qkv(
    const bf16* __restrict__ Xb, const bf16* __restrict__ Wcat,
    const float* __restrict__ bq, const float* __restrict__ bk, const float* __restrict__ bv,
    bf16* __restrict__ Qs, bf16* __restrict__ Ks, bf16* __restrict__ Vt)
{
    __shared__ __align__(16) unsigned char smem[36864];   // 36 KB
    uint4* Al = (uint4*)smem;              // [2][512]
    uint4* Bl = (uint4*)(smem + 16384);    // [2][512]

    const int tid  = threadIdx.x;
    const int w    = tid >> 6;
    const int lane = tid & 63;
    const int col  = lane & 15;
    const int quad = lane >> 4;
    const int m0 = blockIdx.x * 128;
    const int n0 = blockIdx.y * 128;

    const bf16* gA0 = Xb   + (size_t)(m0 + (tid >> 2)) * 512 + (tid & 3) * 8;
    const bf16* gA1 = gA0 + 64 * 512;
    const bf16* gB0 = Wcat + (size_t)(n0 + (tid >> 2)) * 512 + (tid & 3) * 8;
    const bf16* gB1 = gB0 + 64 * 512;

    const floatx4 zf = {0.f, 0.f, 0.f, 0.f};
    floatx4 acc[4][4];
    #pragma unroll
    for (int a = 0; a < 4; ++a)
        #pragma unroll
        for (int b = 0; b < 4; ++b) acc[a][b] = zf;

    Al[tid]       = *(const uint4*)gA0;
    Al[tid + 256] = *(const uint4*)gA1;
    Bl[tid]       = *(const uint4*)gB0;
    Bl[tid + 256] = *(const uint4*)gB1;
    __syncthreads();

    const int mb = (w & 1) * 64;
    const int nb = (w >> 1) * 64;

    int buf = 0;
    for (int kk = 0; kk < 16; ++kk) {
        const int kn = ((kk + 1) & 15) * 32;
        const uint4 pa0 = *(const uint4*)(gA0 + kn);
        const uint4 pa1 = *(const uint4*)(gA1 + kn);
        const uint4 pb0 = *(const uint4*)(gB0 + kn);
        const uint4 pb1 = *(const uint4*)(gB1 + kn);

        const uint4* A4 = Al + buf * 512;
        const uint4* B4 = Bl + buf * 512;
        bf16x8 af[4], bfr[4];
        #pragma unroll
        for (int t = 0; t < 4; ++t) {
            union { uint4 u; bf16x8 v; } ca, cb;
            ca.u = A4[(mb + 16 * t + col) * 4 + quad];
            cb.u = B4[(nb + 16 * t + col) * 4 + quad];
            af[t] = ca.v;
            bfr[t] = cb.v;
        }
        #pragma unroll
        for (int tm = 0; tm < 4; ++tm)
            #pragma unroll
            for (int tn = 0; tn < 4; ++tn)
                acc[tm][tn] = MFMA32(af[tm], bfr[tn], acc[tm][tn]);

        const int nbuf = buf ^ 1;
        Al[nbuf * 512 + tid]       = pa0;
        Al[nbuf * 512 + tid + 256] = pa1;
        Bl[nbuf * 512 + tid]       = pb0;
        Bl[nbuf * 512 + tid + 256] = pb1;
        __syncthreads();
        buf = nbuf;
    }

    // ---- epilogue: wave-private LDS transpose, coalesced 128B stores ----
    bf16* ep = (bf16*)smem + (size_t)w * 64 * 72;   // 9216 B per wave

    const int which = blockIdx.y >> 2;              // 0=Q 1=K 2=V
    const int nbase = (blockIdx.y & 3) * 128 + nb;  // 64-aligned
    const int h  = nbase >> 6;
    const int mw = m0 + mb;
    const int b  = mw >> 12;
    const int s0 = mw & 4095;
    const float qsc = 0.125f * 1.44269504088896f;

    if (which == 2) {
        #pragma unroll
        for (int tn = 0; tn < 4; ++tn) {
            const int d = 16 * tn + col;
            const float bb = bv[nbase + d];
            #pragma unroll
            for (int tm = 0; tm < 4; ++tm) {
                union { bf16 e[4]; uint2 u; } pk;
                #pragma unroll
                for (int r = 0; r < 4; ++r) pk.e[r] = (bf16)(acc[tm][tn][r] + bb);
                *(uint2*)(ep + d * 72 + 16 * tm + 4 * quad) = pk.u;
            }
        }
    } else {
        const float* bias = (which == 0) ? bq : bk;
        const float sc = (which == 0) ? qsc : 1.0f;
        #pragma unroll
        for (int tn = 0; tn < 4; ++tn) {
            const int d = 16 * tn + col;
            const float bb = bias[nbase + d];
            #pragma unroll
            for (int tm = 0; tm < 4; ++tm)
                #pragma unroll
                for (int r = 0; r < 4; ++r)
                    ep[(16 * tm + 4 * quad + r) * 72 + d] = (bf16)((acc[tm][tn][r] + bb) * sc);
        }
    }

    asm volatile("" ::: "memory");

    const int rl = lane >> 3;
    const int ch = lane & 7;
    bf16* gbase;
    size_t rowstride;
    if (which == 2) {
        gbase = Vt + (((size_t)b * 8 + h) * 64) * 4096 + s0;
        rowstride = 4096;
    } else {
        bf16* P = (which == 0) ? Qs : Ks;
        gbase = P + (((size_t)b * 8 + h) * 4096 + s0) * 64;
        rowstride = 64;
    }
    #pragma unroll
    for (int it = 0; it < 8; ++it) {
        const int row = it * 8 + rl;
        const uint4 v = *(const uint4*)(ep + row * 72 + ch * 8);
        *(uint4*)(gbase + (size_t)row * rowstride + ch * 8) = v;
    }
}

// ---------------------------------------------------------------------------
// Kernel 3: attention. NEW (R6): the kernel is LDS-THROUGHPUT-bound (pipe
// accounting from R3/R5 counters: fragment reads + staging = ~120 LDS
// cyc/wave-iter x 1024 wave-iters/CU = 56us of the 83us kernel, +7us bank
// conflicts). Fix: 64 q per wave (4 q-sets of 16) — each K/V fragment read
// now feeds 2x the MFMA work, cutting LDS cycles/CU ~1.66x.
// Shape: 512 blocks x 256 thr = 4 waves (2 key-halves x 2 wq x 64 q),
// same 128-q/block coverage, 2-way in-block split-K, K-step 32, same
// swizzled double-buffered staging (now 128 thr/half staging 2 K-slots +
// 2 V-slots each; slot+128 has identical XOR phase since 16&7==0).
// 2 waves/SIMD, VGPR budget 256 via waves_per_eu(2,2): live set ~190
// (o 64 + aq 32 + frags/prefetch/addr) — forces allocator past 64.
// ---------------------------------------------------------------------------
__global__ __launch_bounds__(256) __attribute__((amdgpu_waves_per_eu(2, 2))) void k_attn(
    const bf16* __restrict__ Qs, const bf16* __restrict__ Ks, const bf16* __restrict__ Vt,
    bf16* __restrict__ att)
{
    __shared__ __align__(16) unsigned char smem[33280];
    uint4* Klds = (uint4*)smem;                 // [half][2][256]
    uint4* Vlds = (uint4*)(smem + 16384);       // [half][2][256]
    float* Of   = (float*)smem;                 // combine: [2 wq][64 lane][16 frag][4]
    float* Ls   = (float*)(smem + 32768);       // [2 wq][4 s][16 col]

    const int tid  = threadIdx.x;     // 0..255
    const int w    = tid >> 6;        // 0..3
    const int hf   = w >> 1;          // key-half: 0 = keys 0..2047, 1 = 2048..4095
    const int wq   = w & 1;           // q-subtile (64 q each)
    const int lane = tid & 63;
    const int col  = lane & 15;
    const int quad = lane >> 4;
    const int i    = blockIdx.x;
    const int bh   = ((i & 7) << 1) | ((i >> 3) & 1);   // 2 heads per XCD
    const int q0   = (i >> 4) * 128 + wq * 64;

    const bf16* Qb = Qs + (size_t)bh * 262144;
    const bf16* Kb = Ks + (size_t)bh * 262144 + (size_t)hf * 2048 * 64;
    const bf16* Vb = Vt + (size_t)bh * 262144 + (size_t)hf * 2048;

    // staging: 128 threads per half (tid<128 <=> hf==0), 2 K + 2 V slots each
    const int t7  = tid & 127;
    const int rK  = t7 >> 3;                       // 0..15
    const int lcK = (t7 & 7) ^ (rK & 7);
    const bf16* gK = Kb + (size_t)rK * 64 + lcK * 8;     // slot t7; t7+128 -> +16 rows
    const int pV  = t7 >> 3;
    const int ccV = (t7 & 7) ^ (pV & 7);
    const int dV  = 2 * pV + (ccV >> 2);
    const int cV  = ccV & 3;
    const bf16* gV = Vb + (size_t)dV * 4096 + cV * 8;    // slot t7; t7+128 -> +32 d-rows

    uint4* Kl2 = Klds + hf * 512;   // this half's [2][256]
    uint4* Vl2 = Vlds + hf * 512;

    // Q fragments (B-operand of S^T MFMA): 4 q-sets x 2 dim-halves
    bf16x8 aq[4][2];
    #pragma unroll
    for (int s = 0; s < 4; ++s)
        #pragma unroll
        for (int c = 0; c < 2; ++c)
            aq[s][c] = *(const bf16x8*)(Qb + (size_t)(q0 + 16 * s + col) * 64 + 32 * c + quad * 8);

    const floatx4 zf = {0.f, 0.f, 0.f, 0.f};
    floatx4 o[4][4];                 // O^T: [qset][d-tile]; lane d=4quad+r, q=col
    float lsum[4] = {0.f, 0.f, 0.f, 0.f};
    #pragma unroll
    for (int s = 0; s < 4; ++s)
        #pragma unroll
        for (int dt = 0; dt < 4; ++dt) o[s][dt] = zf;

    // V b64 read geometry (from the pair-swizzled uint4 tile)
    const int c1 = col & 1, ch2 = col >> 1, qh = quad >> 1, ql = quad & 1;

    Kl2[t7]       = *(const uint4*)gK;
    Kl2[t7 + 128] = *(const uint4*)(gK + 1024);      // +16 rows (same xor phase)
    Vl2[t7]       = *(const uint4*)gV;
    Vl2[t7 + 128] = *(const uint4*)(gV + 131072);    // +32 d-rows
    __syncthreads();

    int buf = 0;
    for (int kt = 0; kt < 2048; kt += 32) {
        const int kn = (kt + 32) & 2047;
        const uint4 kr0 = *(const uint4*)(gK + (size_t)kn * 64);
        const uint4 kr1 = *(const uint4*)(gK + (size_t)kn * 64 + 1024);
        const uint4 vr0 = *(const uint4*)(gV + kn);
        const uint4 vr1 = *(const uint4*)(gV + kn + 131072);

        const uint4* Kl = Kl2 + buf * 256;
        const uint2* Vl = (const uint2*)(Vl2 + buf * 256);

        bf16x8 kf[2][2];
        #pragma unroll
        for (int t = 0; t < 2; ++t)
            #pragma unroll
            for (int c = 0; c < 2; ++c) {
                union { uint4 u; bf16x8 v; } cv;
                cv.u = Kl[(16 * t + col) * 8 + ((quad + 4 * c) ^ (col & 7))];
                kf[t][c] = cv.v;
            }
        // V^T A-fragments, both key-halves packed: vfrag8[dt] slot j holds
        // Vt[d=16dt+col][key = 16*(j>>2) + 4*quad + (j&3)]
        bf16x8 vfrag8[4];
        #pragma unroll
        for (int dt = 0; dt < 4; ++dt) {
            union { uint2 u[2]; bf16x8 v; } cv;
            #pragma unroll
            for (int t = 0; t < 2; ++t) {
                const int slot = (dt * 8 + ch2) * 8 + ((c1 * 4 + 2 * t + qh) ^ ch2);
                cv.u[t] = Vl[slot * 2 + ql];
            }
            vfrag8[dt] = cv.v;
        }

        #pragma unroll
        for (int s = 0; s < 4; ++s) {
            // P^T B-fragment: slot j = exp(score of key 16*(j>>2)+4*quad+(j&3))
            union { bf16 e[8]; bf16x8 v; } pw;
            #pragma unroll
            for (int t = 0; t < 2; ++t) {
                floatx4 sc = MFMA32(kf[t][1], aq[s][1], MFMA32(kf[t][0], aq[s][0], zf));
                const float p0 = __builtin_amdgcn_exp2f(sc[0]);
                const float p1 = __builtin_amdgcn_exp2f(sc[1]);
                const float p2 = __builtin_amdgcn_exp2f(sc[2]);
                const float p3 = __builtin_amdgcn_exp2f(sc[3]);
                lsum[s] += (p0 + p1) + (p2 + p3);
                pw.e[4 * t + 0] = (bf16)p0; pw.e[4 * t + 1] = (bf16)p1;
                pw.e[4 * t + 2] = (bf16)p2; pw.e[4 * t + 3] = (bf16)p3;
            }
            #pragma unroll
            for (int dt = 0; dt < 4; ++dt)
                o[s][dt] = MFMA32(vfrag8[dt], pw.v, o[s][dt]);
        }

        Kl2[(buf ^ 1) * 256 + t7]       = kr0;
        Kl2[(buf ^ 1) * 256 + t7 + 128] = kr1;
        Vl2[(buf ^ 1) * 256 + t7]       = vr0;
        Vl2[(buf ^ 1) * 256 + t7 + 128] = vr1;
        __syncthreads();
        buf ^= 1;
    }

    // ---- partial l reduction (within this half's 2048 keys) ----
    float lv[4];
    #pragma unroll
    for (int s = 0; s < 4; ++s) {
        float v = lsum[s];
        v += __shfl_xor(v, 16, 64);
        v += __shfl_xor(v, 32, 64);
        lv[s] = v;
    }

    // ---- in-block split-K combine (LDS aliases staging bufs; all reads of
    // the staged tiles completed before the final in-loop barrier) ----
    float* op = Of + ((size_t)(wq * 64 + lane)) * 64;
    if (hf == 1) {
        #pragma unroll
        for (int s = 0; s < 4; ++s)
            #pragma unroll
            for (int dt = 0; dt < 4; ++dt) {
                const int f = s * 4 + dt;
                *(floatx4*)(op + ((f + lane) & 15) * 4) = o[s][dt];
            }
        if (quad == 0) {
            #pragma unroll
            for (int s = 0; s < 4; ++s)
                Ls[(wq * 4 + s) * 16 + col] = lv[s];
        }
    }
    __syncthreads();
    if (hf == 0) {
        float inv[4];
        #pragma unroll
        for (int s = 0; s < 4; ++s)
            inv[s] = 1.0f / (lv[s] + Ls[(wq * 4 + s) * 16 + col]);
        const int b  = bh >> 3;
        const int hh = bh & 7;
        #pragma unroll
        for (int s = 0; s < 4; ++s)
            #pragma unroll
            for (int dt = 0; dt < 4; ++dt) {
                const int f = s * 4 + dt;
                const floatx4 po = *(const floatx4*)(op + ((f + lane) & 15) * 4);
                union { bf16 e[4]; uint2 u; } pk;
                #pragma unroll
                for (int r = 0; r < 4; ++r)
                    pk.e[r] = (bf16)((o[s][dt][r] + po[r]) * inv[s]);
                const size_t row = (size_t)b * 4096 + q0 + 16 * s + col;
                *(uint2*)(att + row * 512 + hh * 64 + 16 * dt + 4 * quad) = pk.u;
            }
    }
}

// ---------------------------------------------------------------------------
// Kernel 4: output projection GEMM. out[8192][512] fp32 = att @ Wto^T + bo.
// ---------------------------------------------------------------------------
__global__ __launch_bounds__(256) void k_oproj(
    const bf16* __restrict__ att, const bf16* __restrict__ Wto,
    const float* __restrict__ bo, float* __restrict__ out)
{
    __shared__ uint4 Al[2][512];
    __shared__ uint4 Bl[2][512];

    const int tid  = threadIdx.x;
    const int w    = tid >> 6;
    const int lane = tid & 63;
    const int col  = lane & 15;
    const int quad = lane >> 4;
    const int m0 = blockIdx.x * 128;
    const int n0 = blockIdx.y * 128;

    const bf16* gA0 = att + (size_t)(m0 + (tid >> 2)) * 512 + (tid & 3) * 8;
    const bf16* gA1 = gA0 + 64 * 512;
    const bf16* gB0 = Wto + (size_t)(n0 + (tid >> 2)) * 512 + (tid & 3) * 8;
    const bf16* gB1 = gB0 + 64 * 512;

    const floatx4 zf = {0.f, 0.f, 0.f, 0.f};
    floatx4 acc[4][4];
    #pragma unroll
    for (int a = 0; a < 4; ++a)
        #pragma unroll
        for (int b = 0; b < 4; ++b) acc[a][b] = zf;

    Al[0][tid]       = *(const uint4*)gA0;
    Al[0][tid + 256] = *(const uint4*)gA1;
    Bl[0][tid]       = *(const uint4*)gB0;
    Bl[0][tid + 256] = *(const uint4*)gB1;
    __syncthreads();

    const int mb = (w & 1) * 64;
    const int nb = (w >> 1) * 64;

    int buf = 0;
    for (int kk = 0; kk < 16; ++kk) {
        const int kn = ((kk + 1) & 15) * 32;
        const uint4 pa0 = *(const uint4*)(gA0 + kn);
        const uint4 pa1 = *(const uint4*)(gA1 + kn);
        const uint4 pb0 = *(const uint4*)(gB0 + kn);
        const uint4 pb1 = *(const uint4*)(gB1 + kn);

        const uint4* A4 = Al[buf];
        const uint4* B4 = Bl[buf];
        bf16x8 af[4], bfr[4];
        #pragma unroll
        for (int t = 0; t < 4; ++t) {
            union { uint4 u; bf16x8 v; } ca, cb;
            ca.u = A4[(mb + 16 * t + col) * 4 + quad];
            cb.u = B4[(nb + 16 * t + col) * 4 + quad];
            af[t] = ca.v;
            bfr[t] = cb.v;
        }
        #pragma unroll
        for (int tm = 0; tm < 4; ++tm)
            #pragma unroll
            for (int tn = 0; tn < 4; ++tn)
                acc[tm][tn] = MFMA32(af[tm], bfr[tn], acc[tm][tn]);

        Al[buf ^ 1][tid]       = pa0;
        Al[buf ^ 1][tid + 256] = pa1;
        Bl[buf ^ 1][tid]       = pb0;
        Bl[buf ^ 1][tid + 256] = pb1;
        __syncthreads();
        buf ^= 1;
    }

    #pragma unroll
    for (int tn = 0; tn < 4; ++tn) {
        const int n = n0 + nb + 16 * tn + col;
        const float bb = bo[n];
        #pragma unroll
        for (int tm = 0; tm < 4; ++tm)
            #pragma unroll
            for (int r = 0; r < 4; ++r) {
                const int m = m0 + mb + 16 * tm + quad * 4 + r;
                out[(size_t)m * 512 + n] = acc[tm][tn][r] + bb;
            }
    }
}

// ---------------------------------------------------------------------------
extern "C" void kernel_launch(void* const* d_in, const int* in_sizes, int n_in,
                              void* d_out, int out_size, void* d_ws, size_t ws_size,
                              hipStream_t stream)
{
    const float* X  = (const float*)d_in[0];
    const float* Wq = (const float*)d_in[1];
    const float* bq = (const float*)d_in[2];
    const float* Wk = (const float*)d_in[3];
    const float* bk = (const float*)d_in[4];
    const float* Wv = (const float*)d_in[5];
    const float* bv = (const float*)d_in[6];
    const float* Wo = (const float*)d_in[7];
    const float* bo = (const float*)d_in[8];

    // workspace (bf16 elements): Wcat(3) + Wto + Q + K + Vt + att = 34.1 MB
    bf16* Wtq = (bf16*)d_ws;                   // rows 0..511 of Wcat
    bf16* Wtk = Wtq + 512 * 512;               // rows 512..1023
    bf16* Wtv = Wtk + 512 * 512;               // rows 1024..1535
    bf16* Wto = Wtv + 512 * 512;
    bf16* Qs  = Wto + 512 * 512;               // [16][4096][64]
    bf16* Ks  = Qs + (size_t)16 * 4096 * 64;   // [16][4096][64]
    bf16* Vt  = Ks + (size_t)16 * 4096 * 64;   // [16][64][4096]
    bf16* att = Vt + (size_t)16 * 4096 * 64;   // [8192][512]

    bf16* Xb  = (bf16*)d_out;                  // scratch; consumed by k_qkv,
                                               // d_out rewritten only by k_oproj

    k_transpose<<<dim3(16, 16, 4), 256, 0, stream>>>(Wq, Wk, Wv, Wo, Wtq, Wtk, Wtv, Wto);
    k_cvtx<<<2048, 256, 0, stream>>>(X, Xb);
    k_qkv<<<dim3(64, 12), 256, 0, stream>>>(Xb, Wtq, bq, bk, bv, Qs, Ks, Vt);
    k_attn<<<512, 256, 0, stream>>>(Qs, Ks, Vt, att);
    k_oproj<<<dim3(64, 4), 256, 0, stream>>>(att, Wto, bo, (float*)d_out);
}